// Round 9
// baseline (157.248 us; speedup 1.0000x reference)
//
#include <hip/hip_runtime.h>
#include <stdint.h>

typedef unsigned short u16;
typedef __bf16 bf16_t;
typedef bf16_t bf16x8 __attribute__((ext_vector_type(8)));
typedef float f32x4 __attribute__((ext_vector_type(4)));

static constexpr int P = 65536;  // H*W; D = C = 256

__device__ __forceinline__ float bfbits2f(uint32_t b) {
    union { uint32_t i; float f; } u; u.i = b << 16; return u.f;
}
__device__ __forceinline__ u16 f2bf(float f) {
    union { float f; uint32_t i; } u; u.f = f;
    uint32_t x = u.i + 0x7FFFu + ((u.i >> 16) & 1u);   // RNE
    return (u16)(x >> 16);
}
__device__ __forceinline__ uint32_t pack2(float a, float b) {
    return (uint32_t)f2bf(a) | ((uint32_t)f2bf(b) << 16);
}

// Runtime input-dtype sniff (insurance; verdict on this harness: f32).
__device__ __forceinline__ int detect_bf16_input(const void* Xg) {
    const uint32_t* Xu = (const uint32_t*)Xg;
    const int lane = (int)(threadIdx.x & 63);
    const uint32_t v = Xu[(size_t)lane * 131071u];
    const uint32_t e = (v >> 7) & 0xFFu;
    unsigned long long m = __ballot(e >= 96u && e <= 135u);
    return __popcll(m) >= 40;
}

// Kernel 1: rs[c] = scale[c]*5/max(||w_c||,1e-8)  AND  W -> bf16 row image.
__global__ __launch_bounds__(64) void coshead_prep(
    const void* __restrict__ Xg, const void* __restrict__ Wg,
    const void* __restrict__ Sg, float* __restrict__ rs_ws,
    u16* __restrict__ wbf)
{
    const int c    = (int)blockIdx.x;
    const int lane = (int)threadIdx.x;
    const int bf   = detect_bf16_input(Xg);
    float s;
    uint2 packed;
    if (bf) {
        const uint2 v = *(const uint2*)((const u16*)Wg + (size_t)c * 256 + lane * 4);
        const float a = bfbits2f(v.x & 0xFFFFu), b = bfbits2f(v.x >> 16);
        const float d = bfbits2f(v.y & 0xFFFFu), e = bfbits2f(v.y >> 16);
        s = a * a + b * b + d * d + e * e;
        packed = v;
    } else {
        const f32x4 v = *(const f32x4*)((const float*)Wg + (size_t)c * 256 + lane * 4);
        s = v[0] * v[0] + v[1] * v[1] + v[2] * v[2] + v[3] * v[3];
        packed.x = pack2(v[0], v[1]);
        packed.y = pack2(v[2], v[3]);
    }
    *(uint2*)(wbf + (size_t)c * 256 + lane * 4) = packed;
    s += __shfl_xor(s, 1);  s += __shfl_xor(s, 2);  s += __shfl_xor(s, 4);
    s += __shfl_xor(s, 8);  s += __shfl_xor(s, 16); s += __shfl_xor(s, 32);
    if (lane == 0) {
        const float sc = bf ? bfbits2f((uint32_t)((const u16*)Sg)[c])
                            : ((const float*)Sg)[c];
        rs_ws[c] = sc * 5.0f / fmaxf(sqrtf(s), 1e-8f);
    }
}

// Kernel 2: out[c,p] = (W@X)[c,p] * rs[c] / max(||x_p||,1e-8), f32 out.
// f32 path: DMA-prefetched X ring (T3/T4 pattern, m201-style):
//   - X f32 DMA'd into a 2-deep LDS ring via global_load_lds (ZERO staging
//     registers -> no spill, unlike the R1-R3 register carry).
//   - raw s_barrier + manual waitcnt: vmcnt(0) waits only the CURRENT tile's
//     DMA; the NEXT tile's DMA stays in flight across both barriers and the
//     MFMA phase (~600 cy of HBM latency hidden; today it is 0).
//   - A fragments per-kk direct from the L2-resident bf16 W image (R1/R2-
//     proven mapping) -> no sA, LDS = ring 32K + sB dbuf 16K = 48K, 3 blk/CU.
// bf16 path: R8's proven lockstep kernel verbatim (block-uniform branch).
__global__ __launch_bounds__(256, 3) void coshead_gemm(
    const void* __restrict__ Xg_, const u16* __restrict__ Wbf,
    const float* __restrict__ rs_ws, float* __restrict__ Og)
{
    __shared__ char smem_[49152];
    // f32 path: ring = smem_[0..32K) (2 x 16KB f32 X tiles, [row][pix] 256B rows)
    //           sBd  = smem_[32K..48K) (2 x 8KB swizzled bf16 B tiles)
    // bf path:  sA   = smem_[0..32K), sB = smem_[32K..40K)  (R8 layout)

    const int t  = (int)threadIdx.x;
    const int l  = t & 63;
    const int w  = t >> 6;
    const int p0 = (int)blockIdx.x * 64;
    const int bf = detect_bf16_input(Xg_);

    const int g    = t & 7;      // pixel octet
    const int r    = t >> 3;     // k-pair row 0..31
    const int m16  = l & 15;
    const int quad = l >> 4;

    float ssq[8];
#pragma unroll
    for (int j = 0; j < 8; ++j) ssq[j] = 0.f;
    f32x4 acc[4][4];
#pragma unroll
    for (int a = 0; a < 4; ++a)
#pragma unroll
        for (int b = 0; b < 4; ++b)
#pragma unroll
            for (int i = 0; i < 4; ++i) acc[a][b][i] = 0.f;

    if (!bf) {
        // ================= f32 pipelined path =================
        char* ring = smem_;
        char* sBd  = smem_ + 32768;

        // DMA geometry: per kc, wave w stages rows w*16+j*4+(l>>4), j=0..3;
        // lane l writes ring + w*4096 + j*1024 + l*16 (HW: uniform base +
        // lane*16). Source: X[kc*64+row][p0 + (l&15)*4 .. +3].
        const int lrow16 = l >> 4;
        const int lpix4  = (l & 15) * 4;
        const float* xsrc0 = (const float*)Xg_ + (size_t)(w * 16 + lrow16) * P + p0 + lpix4;

        // A-fragment base (R1/R2-proven direct-L2 mapping)
        const u16* wrow = Wbf + (size_t)(w * 64 + m16) * 256 + quad * 8;

        // prologue: issue DMA for kc=0 into ring[0]
        {
            const float* s0 = xsrc0;   // kc=0
            char* db = ring + w * 4096;
#pragma unroll
            for (int j = 0; j < 4; ++j) {
                __builtin_amdgcn_global_load_lds(
                    (const __attribute__((address_space(1))) void*)(s0 + (size_t)(j * 4) * P),
                    (__attribute__((address_space(3))) void*)(db + j * 1024),
                    16, 0, 0);
            }
        }

        for (int kc = 0; kc < 4; ++kc) {
            const int cur = kc & 1;
            // ---- own DMA[kc] done, then cross-wave sync ----
            asm volatile("s_waitcnt vmcnt(0)" ::: "memory");
            __builtin_amdgcn_sched_barrier(0);
            __builtin_amdgcn_s_barrier();          // ring[cur] ready everywhere

            // ---- issue A fragments (regs, L2) + DMA[kc+1] (survives barriers) ----
            bf16x8 afr[2][4];
#pragma unroll
            for (int kk = 0; kk < 2; ++kk)
#pragma unroll
                for (int tm = 0; tm < 4; ++tm)
                    afr[kk][tm] = *(const bf16x8*)(wrow + kc * 64 + kk * 32 + tm * 4096);
            if (kc < 3) {
                const float* s1 = xsrc0 + (size_t)((kc + 1) * 64) * P;
                char* db = ring + (cur ^ 1) * 16384 + w * 4096;
#pragma unroll
                for (int j = 0; j < 4; ++j) {
                    __builtin_amdgcn_global_load_lds(
                        (const __attribute__((address_space(1))) void*)(s1 + (size_t)(j * 4) * P),
                        (__attribute__((address_space(3))) void*)(db + j * 1024),
                        16, 0, 0);
                }
            }

            // ---- stage ring[cur] -> sBd[cur]: ssq + pack + swizzled write ----
            {
                const char* rg = ring + cur * 16384;
                const int ro = (2 * r) * 256 + g * 32;
                const f32x4 c0  = *(const f32x4*)(rg + ro);
                const f32x4 c1  = *(const f32x4*)(rg + ro + 16);
                const f32x4 d0v = *(const f32x4*)(rg + ro + 256);
                const f32x4 d1v = *(const f32x4*)(rg + ro + 256 + 16);
                const float f0[8] = {c0[0], c0[1], c0[2], c0[3], c1[0], c1[1], c1[2], c1[3]};
                const float f1[8] = {d0v[0], d0v[1], d0v[2], d0v[3], d1v[0], d1v[1], d1v[2], d1v[3]};
                char* sBw = sBd + cur * 8192;
#pragma unroll
                for (int j = 0; j < 8; ++j) {
                    ssq[j] += f0[j] * f0[j] + f1[j] * f1[j];
                    const int pix = g * 8 + j;
                    *(uint32_t*)(sBw + pix * 128 + (((r >> 2) ^ (pix & 7) ^ g) * 16) + (r & 3) * 4) =
                        pack2(f0[j], f1[j]);
                }
            }
            asm volatile("s_waitcnt lgkmcnt(0)" ::: "memory");
            __builtin_amdgcn_sched_barrier(0);
            __builtin_amdgcn_s_barrier();          // sBd[cur] visible; DMA[kc+1] in flight

            // ---- MFMA: 2 K=32 steps; compiler inserts counted af waits ----
            const char* sBw = sBd + cur * 8192;
#pragma unroll
            for (int kk = 0; kk < 2; ++kk) {
                bf16x8 bfr[4];
#pragma unroll
                for (int tn = 0; tn < 4; ++tn) {
                    const int pix = tn * 16 + m16;
                    bfr[tn] = *(const bf16x8*)(sBw + pix * 128 +
                               (((kk * 4 + quad) ^ (pix & 7) ^ (pix >> 3)) * 16));
                }
#pragma unroll
                for (int tm = 0; tm < 4; ++tm)
#pragma unroll
                    for (int tn = 0; tn < 4; ++tn)
                        acc[tm][tn] = __builtin_amdgcn_mfma_f32_16x16x32_bf16(
                            afr[kk][tm], bfr[tn], acc[tm][tn], 0, 0, 0);
            }
        }
        __syncthreads();   // all MFMA reads done before LDS reuse (nothing in flight)
    } else {
        // ================= bf16 insurance path (R8 verbatim) =================
        char* sA = smem_;
        char* sB = smem_ + 32768;
        const int lrow = l >> 3;
        const int gsl  = (l & 7) ^ lrow;
        const u16* wsrc = Wbf + ((size_t)(w * 8 + lrow) << 8) + gsl * 8;
        char* ldsA = sA + w * 1024;

        for (int kc = 0; kc < 4; ++kc) {
#pragma unroll
            for (int j = 0; j < 8; ++j) {
                __builtin_amdgcn_global_load_lds(
                    (const __attribute__((address_space(1))) void*)(wsrc + j * 8192 + kc * 64),
                    (__attribute__((address_space(3))) void*)(ldsA + j * 4096),
                    16, 0, 0);
            }
            const u16* xp = (const u16*)Xg_ + (size_t)(2 * r + kc * 64) * P + p0 + g * 8;
            const uint4 v0 = *(const uint4*)xp;
            const uint4 v1 = *(const uint4*)(xp + P);
            const uint32_t e0[4] = {v0.x, v0.y, v0.z, v0.w};
            const uint32_t e1[4] = {v1.x, v1.y, v1.z, v1.w};
#pragma unroll
            for (int d = 0; d < 4; ++d) {
                const float f00 = bfbits2f(e0[d] & 0xFFFFu), f01 = bfbits2f(e0[d] >> 16);
                const float f10 = bfbits2f(e1[d] & 0xFFFFu), f11 = bfbits2f(e1[d] >> 16);
                ssq[2 * d]     += f00 * f00 + f10 * f10;
                ssq[2 * d + 1] += f01 * f01 + f11 * f11;
                const uint32_t d0 = (e0[d] & 0xFFFFu) | (e1[d] << 16);
                const uint32_t d1 = (e0[d] >> 16) | (e1[d] & 0xFFFF0000u);
                const int pj0 = g * 8 + 2 * d, pj1 = pj0 + 1;
                *(uint32_t*)(sB + pj0 * 128 + (((r >> 2) ^ (pj0 & 7) ^ g) * 16) + (r & 3) * 4) = d0;
                *(uint32_t*)(sB + pj1 * 128 + (((r >> 2) ^ (pj1 & 7) ^ g) * 16) + (r & 3) * 4) = d1;
            }
            __syncthreads();
#pragma unroll
            for (int kk = 0; kk < 2; ++kk) {
                bf16x8 af[4], bfr[4];
#pragma unroll
                for (int tm = 0; tm < 4; ++tm) {
                    const int row = w * 64 + tm * 16 + m16;
                    af[tm] = *(const bf16x8*)(sA + row * 128 + (((kk * 4 + quad) ^ (row & 7)) * 16));
                }
#pragma unroll
                for (int tn = 0; tn < 4; ++tn) {
                    const int pix = tn * 16 + m16;
                    bfr[tn] = *(const bf16x8*)(sB + pix * 128 +
                               (((kk * 4 + quad) ^ (pix & 7) ^ (pix >> 3)) * 16));
                }
#pragma unroll
                for (int tm = 0; tm < 4; ++tm)
#pragma unroll
                    for (int tn = 0; tn < 4; ++tn)
                        acc[tm][tn] = __builtin_amdgcn_mfma_f32_16x16x32_bf16(
                            af[tm], bfr[tn], acc[tm][tn], 0, 0, 0);
            }
            __syncthreads();
        }
    }

    // ---- epilogue: x-norms via LDS transpose-reduce (bit-identical order) ----
    float* xs   = (float*)smem_;            // [32][64] partial ssq
    float* xinv = (float*)(smem_ + 32768);  // [64]
#pragma unroll
    for (int j = 0; j < 8; ++j) xs[r * 64 + g * 8 + j] = ssq[j];
    __syncthreads();
    if (t < 64) {
        float sx = 0.f;
#pragma unroll
        for (int rr = 0; rr < 32; ++rr) sx += xs[rr * 64 + t];
        xinv[t] = 1.0f / fmaxf(sqrtf(sx), 1e-8f);
    }
    __syncthreads();

    // ---- scaled f32 store. class = w*64+tm*16+quad*4+i ; pixel = p0+tn*16+m16 ----
    float inv4[4];
#pragma unroll
    for (int tn = 0; tn < 4; ++tn) inv4[tn] = xinv[tn * 16 + m16];
#pragma unroll
    for (int tm = 0; tm < 4; ++tm) {
        const int cbase = w * 64 + tm * 16 + quad * 4;
        const f32x4 rs4 = *(const f32x4*)(rs_ws + cbase);
#pragma unroll
        for (int tn = 0; tn < 4; ++tn) {
#pragma unroll
            for (int i = 0; i < 4; ++i) {
                Og[(size_t)(cbase + i) * P + p0 + tn * 16 + m16] =
                    acc[tm][tn][i] * rs4[i] * inv4[tn];
            }
        }
    }
}

extern "C" void kernel_launch(void* const* d_in, const int* in_sizes, int n_in,
                              void* d_out, int out_size, void* d_ws, size_t ws_size,
                              hipStream_t stream) {
    (void)out_size; (void)ws_size;
    const void* X = d_in[0];
    const void* W = d_in[1];
    const void* S = d_in[2];
    for (int i = 0; i < n_in; ++i) {
        if (in_sizes[i] == 256 * 65536) X = d_in[i];
        else if (in_sizes[i] == 256 * 256) W = d_in[i];
        else if (in_sizes[i] == 256)      S = d_in[i];
    }
    float* rs  = (float*)d_ws;
    u16*   wbf = (u16*)((char*)d_ws + 1024);   // 128 KB bf16 W image
    coshead_prep<<<dim3(256), dim3(64), 0, stream>>>(X, W, S, rs, wbf);
    coshead_gemm<<<dim3(1024), dim3(256), 0, stream>>>(X, wbf, rs, (float*)d_out);
}

// Round 10
// 142.724 us; speedup vs baseline: 1.1018x; 1.1018x over previous
//
#include <hip/hip_runtime.h>
#include <stdint.h>

typedef unsigned short u16;
typedef __bf16 bf16_t;
typedef bf16_t bf16x8 __attribute__((ext_vector_type(8)));
typedef float f32x4 __attribute__((ext_vector_type(4)));

static constexpr int P = 65536;  // H*W; D = C = 256

__device__ __forceinline__ float bfbits2f(uint32_t b) {
    union { uint32_t i; float f; } u; u.i = b << 16; return u.f;
}
__device__ __forceinline__ u16 f2bf(float f) {
    union { float f; uint32_t i; } u; u.f = f;
    uint32_t x = u.i + 0x7FFFu + ((u.i >> 16) & 1u);   // RNE
    return (u16)(x >> 16);
}
__device__ __forceinline__ uint32_t pack2(float a, float b) {
    return (uint32_t)f2bf(a) | ((uint32_t)f2bf(b) << 16);
}

// Runtime input-dtype sniff (insurance; verdict on this harness: f32).
__device__ __forceinline__ int detect_bf16_input(const void* Xg) {
    const uint32_t* Xu = (const uint32_t*)Xg;
    const int lane = (int)(threadIdx.x & 63);
    const uint32_t v = Xu[(size_t)lane * 131071u];
    const uint32_t e = (v >> 7) & 0xFFu;
    unsigned long long m = __ballot(e >= 96u && e <= 135u);
    return __popcll(m) >= 40;
}

// Kernel 1: rs[c] = scale[c]*5/max(||w_c||,1e-8)  AND  W -> bf16 row image.
__global__ __launch_bounds__(64) void coshead_prep(
    const void* __restrict__ Xg, const void* __restrict__ Wg,
    const void* __restrict__ Sg, float* __restrict__ rs_ws,
    u16* __restrict__ wbf)
{
    const int c    = (int)blockIdx.x;
    const int lane = (int)threadIdx.x;
    const int bf   = detect_bf16_input(Xg);
    float s;
    uint2 packed;
    if (bf) {
        const uint2 v = *(const uint2*)((const u16*)Wg + (size_t)c * 256 + lane * 4);
        const float a = bfbits2f(v.x & 0xFFFFu), b = bfbits2f(v.x >> 16);
        const float d = bfbits2f(v.y & 0xFFFFu), e = bfbits2f(v.y >> 16);
        s = a * a + b * b + d * d + e * e;
        packed = v;
    } else {
        const f32x4 v = *(const f32x4*)((const float*)Wg + (size_t)c * 256 + lane * 4);
        s = v[0] * v[0] + v[1] * v[1] + v[2] * v[2] + v[3] * v[3];
        packed.x = pack2(v[0], v[1]);
        packed.y = pack2(v[2], v[3]);
    }
    *(uint2*)(wbf + (size_t)c * 256 + lane * 4) = packed;
    s += __shfl_xor(s, 1);  s += __shfl_xor(s, 2);  s += __shfl_xor(s, 4);
    s += __shfl_xor(s, 8);  s += __shfl_xor(s, 16); s += __shfl_xor(s, 32);
    if (lane == 0) {
        const float sc = bf ? bfbits2f((uint32_t)((const u16*)Sg)[c])
                            : ((const float*)Sg)[c];
        rs_ws[c] = sc * 5.0f / fmaxf(sqrtf(s), 1e-8f);
    }
}

// Kernel 2: out[c,p] = (W@X)[c,p] * rs[c] / max(||x_p||,1e-8), f32 out.
// f32 path — single-barrier software pipeline obeying all 4 spill lessons:
//   - sB double-buffered (2 x 8 KB). Per kc: barrier -> issue X[kc+1] loads
//     -> MFMA from sB[cur] -> pack carry -> sB[cur^1]. Writes target the
//     buffer nobody reads => NO trailing barrier; carry regs (16) live only
//     within one body, never across a barrier (R3 lesson).
//   - A per-kk DIRECT from the L2-resident bf16 W image; '#pragma unroll 1'
//     on kk forbids the 32-reg af hoist (R1/R2/R9 spill trigger).
//   - LDS 24.5 KB; (256,3).
// bf16 path: R8's proven lockstep kernel verbatim.
__global__ __launch_bounds__(256, 3) void coshead_gemm(
    const void* __restrict__ Xg_, const u16* __restrict__ Wbf,
    const float* __restrict__ rs_ws, float* __restrict__ Og)
{
    __shared__ char smem_[40960];
    // f32 path: sBd = [0,16K) dbuf; xs = [16K,24K); xinv = [24K,24K+256)
    // bf16 path: sA = [0,32K), sB = [32K,40K)  (R8 layout)

    const int t  = (int)threadIdx.x;
    const int l  = t & 63;
    const int w  = t >> 6;
    const int p0 = (int)blockIdx.x * 64;
    const int bf = detect_bf16_input(Xg_);

    const int g    = t & 7;      // pixel octet
    const int r    = t >> 3;     // k-pair row 0..31
    const int m16  = l & 15;
    const int quad = l >> 4;

    float ssq[8];
#pragma unroll
    for (int j = 0; j < 8; ++j) ssq[j] = 0.f;
    f32x4 acc[4][4];
#pragma unroll
    for (int a = 0; a < 4; ++a)
#pragma unroll
        for (int b = 0; b < 4; ++b)
#pragma unroll
            for (int i = 0; i < 4; ++i) acc[a][b][i] = 0.f;

    if (!bf) {
        // ================= f32 pipelined path =================
        char* sBd = smem_;
        const u16* wrow = Wbf + (size_t)(w * 64 + m16) * 256 + quad * 8;
        const float* xbase = (const float*)Xg_ + (size_t)(2 * r) * P + p0 + g * 8;

        // ---- prologue: load + pack kc=0 into sBd[0] ----
        {
            const float* xp = xbase;
            const f32x4 c0  = *(const f32x4*)xp;
            const f32x4 c1  = *(const f32x4*)(xp + 4);
            const f32x4 d0v = *(const f32x4*)(xp + P);
            const f32x4 d1v = *(const f32x4*)(xp + P + 4);
            const float f0[8] = {c0[0], c0[1], c0[2], c0[3], c1[0], c1[1], c1[2], c1[3]};
            const float f1[8] = {d0v[0], d0v[1], d0v[2], d0v[3], d1v[0], d1v[1], d1v[2], d1v[3]};
#pragma unroll
            for (int j = 0; j < 8; ++j) {
                ssq[j] += f0[j] * f0[j] + f1[j] * f1[j];
                const int pix = g * 8 + j;
                *(uint32_t*)(sBd + pix * 128 + (((r >> 2) ^ (pix & 7) ^ g) * 16) + (r & 3) * 4) =
                    pack2(f0[j], f1[j]);
            }
        }

        for (int kc = 0; kc < 4; ++kc) {
            const int cur = kc & 1;
            __syncthreads();   // sBd[cur] visible to all waves

            // ---- issue next tile's X loads (consumed later THIS body;
            //      never live across a barrier) ----
            f32x4 rA, rB, rC, rD;
            if (kc < 3) {
                const float* xp = xbase + (size_t)((kc + 1) * 64) * P;
                rA = *(const f32x4*)xp;
                rB = *(const f32x4*)(xp + 4);
                rC = *(const f32x4*)(xp + P);
                rD = *(const f32x4*)(xp + P + 4);
            }

            // ---- MFMA from sBd[cur]; A per-kk direct from L2 W image.
            //      unroll 1 => af hoist impossible (spill lesson) ----
            const char* sBw = sBd + cur * 8192;
#pragma unroll 1
            for (int kk = 0; kk < 2; ++kk) {
                bf16x8 af[4], bfr[4];
#pragma unroll
                for (int tm = 0; tm < 4; ++tm)
                    af[tm] = *(const bf16x8*)(wrow + kc * 64 + kk * 32 + tm * 4096);
#pragma unroll
                for (int tn = 0; tn < 4; ++tn) {
                    const int pix = tn * 16 + m16;
                    bfr[tn] = *(const bf16x8*)(sBw + pix * 128 +
                               (((kk * 4 + quad) ^ (pix & 7) ^ (pix >> 3)) * 16));
                }
#pragma unroll
                for (int tm = 0; tm < 4; ++tm)
#pragma unroll
                    for (int tn = 0; tn < 4; ++tn)
                        acc[tm][tn] = __builtin_amdgcn_mfma_f32_16x16x32_bf16(
                            af[tm], bfr[tn], acc[tm][tn], 0, 0, 0);
            }

            // ---- pack carry -> sBd[cur^1] (nobody reads it this kc) ----
            if (kc < 3) {
                const float f0[8] = {rA[0], rA[1], rA[2], rA[3], rB[0], rB[1], rB[2], rB[3]};
                const float f1[8] = {rC[0], rC[1], rC[2], rC[3], rD[0], rD[1], rD[2], rD[3]};
                char* sBn = sBd + (cur ^ 1) * 8192;
#pragma unroll
                for (int j = 0; j < 8; ++j) {
                    ssq[j] += f0[j] * f0[j] + f1[j] * f1[j];
                    const int pix = g * 8 + j;
                    *(uint32_t*)(sBn + pix * 128 + (((r >> 2) ^ (pix & 7) ^ g) * 16) + (r & 3) * 4) =
                        pack2(f0[j], f1[j]);
                }
            }
        }
        __syncthreads();   // MFMA reads done before xs overwrites smem_
    } else {
        // ================= bf16 insurance path (R8 verbatim) =================
        char* sA = smem_;
        char* sB = smem_ + 32768;
        const int lrow = l >> 3;
        const int gsl  = (l & 7) ^ lrow;
        const u16* wsrc = Wbf + ((size_t)(w * 8 + lrow) << 8) + gsl * 8;
        char* ldsA = sA + w * 1024;

        for (int kc = 0; kc < 4; ++kc) {
#pragma unroll
            for (int j = 0; j < 8; ++j) {
                __builtin_amdgcn_global_load_lds(
                    (const __attribute__((address_space(1))) void*)(wsrc + j * 8192 + kc * 64),
                    (__attribute__((address_space(3))) void*)(ldsA + j * 4096),
                    16, 0, 0);
            }
            const u16* xp = (const u16*)Xg_ + (size_t)(2 * r + kc * 64) * P + p0 + g * 8;
            const uint4 v0 = *(const uint4*)xp;
            const uint4 v1 = *(const uint4*)(xp + P);
            const uint32_t e0[4] = {v0.x, v0.y, v0.z, v0.w};
            const uint32_t e1[4] = {v1.x, v1.y, v1.z, v1.w};
#pragma unroll
            for (int d = 0; d < 4; ++d) {
                const float f00 = bfbits2f(e0[d] & 0xFFFFu), f01 = bfbits2f(e0[d] >> 16);
                const float f10 = bfbits2f(e1[d] & 0xFFFFu), f11 = bfbits2f(e1[d] >> 16);
                ssq[2 * d]     += f00 * f00 + f10 * f10;
                ssq[2 * d + 1] += f01 * f01 + f11 * f11;
                const uint32_t d0 = (e0[d] & 0xFFFFu) | (e1[d] << 16);
                const uint32_t d1 = (e0[d] >> 16) | (e1[d] & 0xFFFF0000u);
                const int pj0 = g * 8 + 2 * d, pj1 = pj0 + 1;
                *(uint32_t*)(sB + pj0 * 128 + (((r >> 2) ^ (pj0 & 7) ^ g) * 16) + (r & 3) * 4) = d0;
                *(uint32_t*)(sB + pj1 * 128 + (((r >> 2) ^ (pj1 & 7) ^ g) * 16) + (r & 3) * 4) = d1;
            }
            __syncthreads();
#pragma unroll
            for (int kk = 0; kk < 2; ++kk) {
                bf16x8 af[4], bfr[4];
#pragma unroll
                for (int tm = 0; tm < 4; ++tm) {
                    const int row = w * 64 + tm * 16 + m16;
                    af[tm] = *(const bf16x8*)(sA + row * 128 + (((kk * 4 + quad) ^ (row & 7)) * 16));
                }
#pragma unroll
                for (int tn = 0; tn < 4; ++tn) {
                    const int pix = tn * 16 + m16;
                    bfr[tn] = *(const bf16x8*)(sB + pix * 128 +
                               (((kk * 4 + quad) ^ (pix & 7) ^ (pix >> 3)) * 16));
                }
#pragma unroll
                for (int tm = 0; tm < 4; ++tm)
#pragma unroll
                    for (int tn = 0; tn < 4; ++tn)
                        acc[tm][tn] = __builtin_amdgcn_mfma_f32_16x16x32_bf16(
                            af[tm], bfr[tn], acc[tm][tn], 0, 0, 0);
            }
            __syncthreads();
        }
    }

    // ---- epilogue: x-norms via LDS transpose-reduce (bit-identical order) ----
    float* xs   = (float*)smem_;            // [32][64] partial ssq
    float* xinv = (float*)(smem_ + 24576);  // [64] (f32 path) / reuse high LDS
#pragma unroll
    for (int j = 0; j < 8; ++j) xs[r * 64 + g * 8 + j] = ssq[j];
    __syncthreads();
    if (t < 64) {
        float sx = 0.f;
#pragma unroll
        for (int rr = 0; rr < 32; ++rr) sx += xs[rr * 64 + t];
        xinv[t] = 1.0f / fmaxf(sqrtf(sx), 1e-8f);
    }
    __syncthreads();

    // ---- scaled f32 store. class = w*64+tm*16+quad*4+i ; pixel = p0+tn*16+m16 ----
    float inv4[4];
#pragma unroll
    for (int tn = 0; tn < 4; ++tn) inv4[tn] = xinv[tn * 16 + m16];
#pragma unroll
    for (int tm = 0; tm < 4; ++tm) {
        const int cbase = w * 64 + tm * 16 + quad * 4;
        const f32x4 rs4 = *(const f32x4*)(rs_ws + cbase);
#pragma unroll
        for (int tn = 0; tn < 4; ++tn) {
#pragma unroll
            for (int i = 0; i < 4; ++i) {
                Og[(size_t)(cbase + i) * P + p0 + tn * 16 + m16] =
                    acc[tm][tn][i] * rs4[i] * inv4[tn];
            }
        }
    }
}

extern "C" void kernel_launch(void* const* d_in, const int* in_sizes, int n_in,
                              void* d_out, int out_size, void* d_ws, size_t ws_size,
                              hipStream_t stream) {
    (void)out_size; (void)ws_size;
    const void* X = d_in[0];
    const void* W = d_in[1];
    const void* S = d_in[2];
    for (int i = 0; i < n_in; ++i) {
        if (in_sizes[i] == 256 * 65536) X = d_in[i];
        else if (in_sizes[i] == 256 * 256) W = d_in[i];
        else if (in_sizes[i] == 256)      S = d_in[i];
    }
    float* rs  = (float*)d_ws;
    u16*   wbf = (u16*)((char*)d_ws + 1024);   // 128 KB bf16 W image
    coshead_prep<<<dim3(256), dim3(64), 0, stream>>>(X, W, S, rs, wbf);
    coshead_gemm<<<dim3(1024), dim3(256), 0, stream>>>(X, wbf, rs, (float*)d_out);
}

// Round 12
// 134.041 us; speedup vs baseline: 1.1731x; 1.0648x over previous
//
#include <hip/hip_runtime.h>
#include <stdint.h>

typedef unsigned short u16;
typedef __bf16 bf16_t;
typedef bf16_t bf16x8 __attribute__((ext_vector_type(8)));
typedef float f32x4 __attribute__((ext_vector_type(4)));

static constexpr int P = 65536;  // H*W; D = C = 256

__device__ __forceinline__ float bfbits2f(uint32_t b) {
    union { uint32_t i; float f; } u; u.i = b << 16; return u.f;
}
__device__ __forceinline__ u16 f2bf(float f) {
    union { float f; uint32_t i; } u; u.f = f;
    uint32_t x = u.i + 0x7FFFu + ((u.i >> 16) & 1u);   // RNE
    return (u16)(x >> 16);
}
__device__ __forceinline__ uint32_t pack2(float a, float b) {
    return (uint32_t)f2bf(a) | ((uint32_t)f2bf(b) << 16);
}

// Runtime input-dtype sniff (insurance; verdict on this harness: f32).
__device__ __forceinline__ int detect_bf16_input(const void* Xg) {
    const uint32_t* Xu = (const uint32_t*)Xg;
    const int lane = (int)(threadIdx.x & 63);
    const uint32_t v = Xu[(size_t)lane * 131071u];
    const uint32_t e = (v >> 7) & 0xFFu;
    unsigned long long m = __ballot(e >= 96u && e <= 135u);
    return __popcll(m) >= 40;
}

// Kernel 1: rs[c] = scale[c]*5/max(||w_c||,1e-8)  AND  W -> bf16 row image.
__global__ __launch_bounds__(64) void coshead_prep(
    const void* __restrict__ Xg, const void* __restrict__ Wg,
    const void* __restrict__ Sg, float* __restrict__ rs_ws,
    u16* __restrict__ wbf)
{
    const int c    = (int)blockIdx.x;
    const int lane = (int)threadIdx.x;
    const int bf   = detect_bf16_input(Xg);
    float s;
    uint2 packed;
    if (bf) {
        const uint2 v = *(const uint2*)((const u16*)Wg + (size_t)c * 256 + lane * 4);
        const float a = bfbits2f(v.x & 0xFFFFu), b = bfbits2f(v.x >> 16);
        const float d = bfbits2f(v.y & 0xFFFFu), e = bfbits2f(v.y >> 16);
        s = a * a + b * b + d * d + e * e;
        packed = v;
    } else {
        const f32x4 v = *(const f32x4*)((const float*)Wg + (size_t)c * 256 + lane * 4);
        s = v[0] * v[0] + v[1] * v[1] + v[2] * v[2] + v[3] * v[3];
        packed.x = pack2(v[0], v[1]);
        packed.y = pack2(v[2], v[3]);
    }
    *(uint2*)(wbf + (size_t)c * 256 + lane * 4) = packed;
    s += __shfl_xor(s, 1);  s += __shfl_xor(s, 2);  s += __shfl_xor(s, 4);
    s += __shfl_xor(s, 8);  s += __shfl_xor(s, 16); s += __shfl_xor(s, 32);
    if (lane == 0) {
        const float sc = bf ? bfbits2f((uint32_t)((const u16*)Sg)[c])
                            : ((const float*)Sg)[c];
        rs_ws[c] = sc * 5.0f / fmaxf(sqrtf(s), 1e-8f);
    }
}

// Kernel 2: out[c,p] = (W@X)[c,p] * rs[c] / max(||x_p||,1e-8), f32 out.
// R8 champion structure (lockstep, 2 barriers/kc, sA via global_load_lds,
// in-loop X loads) RETILED to 256 classes x 32 pixels per block, acc[4][2]:
//   - acc drops 64 -> 32 AGPR; total regs ~112 <= 128 boundary
//     => 4 waves/SIMD (16 waves/CU, 4 blocks/CU) vs 2 in ALL prior rounds
//     (the VGPR_Count 84+64=148 > 128 was the invariant occupancy limiter).
//   - grid 2048 = 8 blocks/CU of work = 2 full residency rounds, no tail.
//   - __launch_bounds__(256,4) forces the cap (spill tripwire: WRITE>80MB).
__global__ __launch_bounds__(256, 4) void coshead_gemm(
    const void* __restrict__ Xg_, const u16* __restrict__ Wbf,
    const float* __restrict__ rs_ws, float* __restrict__ Og)
{
    __shared__ char smem_[36864];
    char* sA = smem_;            // [256 rows][8 slots x 16 B]; slot s holds granule s^(row&7)
    char* sB = smem_ + 32768;    // [32 pix][8 slots x 16 B], swizzled (4 KB)

    const int t  = (int)threadIdx.x;
    const int l  = t & 63;
    const int w  = t >> 6;
    const int p0 = (int)blockIdx.x * 32;
    const int bf = detect_bf16_input(Xg_);

    const int g    = t & 7;      // pixel QUARTET (4 pix each: g*4..g*4+3)
    const int r    = t >> 3;     // k-pair row 0..31
    const int m16  = l & 15;
    const int quad = l >> 4;

    // sA staging map (R8-proven): call j covers rows j*32 + w*8 .. +7.
    const int lrow = l >> 3;
    const int gsl  = (l & 7) ^ lrow;
    const u16* wsrc = Wbf + ((size_t)(w * 8 + lrow) << 8) + gsl * 8;
    char* ldsA = sA + w * 1024;

    float ssq[4];
#pragma unroll
    for (int j = 0; j < 4; ++j) ssq[j] = 0.f;
    f32x4 acc[4][2];
#pragma unroll
    for (int a = 0; a < 4; ++a)
#pragma unroll
        for (int b = 0; b < 2; ++b)
#pragma unroll
            for (int i = 0; i < 4; ++i) acc[a][b][i] = 0.f;

    for (int kc = 0; kc < 4; ++kc) {
        // ---- A: 8 x 1 KB wave-DMA from the L2-resident bf16 W image ----
#pragma unroll
        for (int j = 0; j < 8; ++j) {
            __builtin_amdgcn_global_load_lds(
                (const __attribute__((address_space(1))) void*)(wsrc + j * 8192 + kc * 64),
                (__attribute__((address_space(3))) void*)(ldsA + j * 4096),
                16, 0, 0);
        }

        if (bf) {
            // ---- insurance path: bf16 input, 4 pix x 2 rows ----
            const u16* xp = (const u16*)Xg_ + (size_t)(2 * r + kc * 64) * P + p0 + g * 4;
            const uint2 v0 = *(const uint2*)xp;
            const uint2 v1 = *(const uint2*)(xp + P);
            const uint32_t e0[2] = {v0.x, v0.y};
            const uint32_t e1[2] = {v1.x, v1.y};
#pragma unroll
            for (int d = 0; d < 2; ++d) {
                const float f00 = bfbits2f(e0[d] & 0xFFFFu), f01 = bfbits2f(e0[d] >> 16);
                const float f10 = bfbits2f(e1[d] & 0xFFFFu), f11 = bfbits2f(e1[d] >> 16);
                ssq[2 * d]     += f00 * f00 + f10 * f10;
                ssq[2 * d + 1] += f01 * f01 + f11 * f11;
                const uint32_t d0 = (e0[d] & 0xFFFFu) | (e1[d] << 16);
                const uint32_t d1 = (e0[d] >> 16) | (e1[d] & 0xFFFF0000u);
                const int pj0 = g * 4 + 2 * d, pj1 = pj0 + 1;
                *(uint32_t*)(sB + pj0 * 128 + (((r >> 2) ^ (pj0 & 7) ^ (pj0 >> 3)) * 16) + (r & 3) * 4) = d0;
                *(uint32_t*)(sB + pj1 * 128 + (((r >> 2) ^ (pj1 & 7) ^ (pj1 >> 3)) * 16) + (r & 3) * 4) = d1;
            }
        } else {
            // ---- f32 path: 4 pix x 2 rows, load in-loop, consume immediately ----
            const float* xp = (const float*)Xg_ + (size_t)(2 * r + kc * 64) * P + p0 + g * 4;
            const f32x4 c0 = *(const f32x4*)xp;        // row 2r
            const f32x4 d0 = *(const f32x4*)(xp + P);  // row 2r+1
#pragma unroll
            for (int j = 0; j < 4; ++j) {
                ssq[j] += c0[j] * c0[j] + d0[j] * d0[j];
                const int pix = g * 4 + j;
                *(uint32_t*)(sB + pix * 128 + (((r >> 2) ^ (pix & 7) ^ (pix >> 3)) * 16) + (r & 3) * 4) =
                    pack2(c0[j], d0[j]);
            }
        }
        __syncthreads();   // sA DMA drained + sB writes visible

        // ---- MFMA: 2 K=32 steps; wave tile 64 classes x 32 pixels ----
#pragma unroll
        for (int kk = 0; kk < 2; ++kk) {
            bf16x8 af[4], bfr[2];
#pragma unroll
            for (int tm = 0; tm < 4; ++tm) {
                const int row = w * 64 + tm * 16 + m16;
                af[tm] = *(const bf16x8*)(sA + row * 128 + (((kk * 4 + quad) ^ (row & 7)) * 16));
            }
#pragma unroll
            for (int tn = 0; tn < 2; ++tn) {
                const int pix = tn * 16 + m16;
                bfr[tn] = *(const bf16x8*)(sB + pix * 128 +
                           (((kk * 4 + quad) ^ (pix & 7) ^ (pix >> 3)) * 16));
            }
#pragma unroll
            for (int tm = 0; tm < 4; ++tm)
#pragma unroll
                for (int tn = 0; tn < 2; ++tn)
                    acc[tm][tn] = __builtin_amdgcn_mfma_f32_16x16x32_bf16(
                        af[tm], bfr[tn], acc[tm][tn], 0, 0, 0);
        }
        __syncthreads();   // protects sA/sB rewrite next kc
    }

    // ---- epilogue: x-norms via LDS transpose-reduce (same order per pixel) ----
    float* xs   = (float*)smem_;            // [32][32] partial ssq (4 KB, over sA)
    float* xinv = (float*)(smem_ + 32768);  // [32] (over sB, dead now)
#pragma unroll
    for (int j = 0; j < 4; ++j) xs[r * 32 + g * 4 + j] = ssq[j];
    __syncthreads();
    if (t < 32) {
        float sx = 0.f;
#pragma unroll
        for (int rr = 0; rr < 32; ++rr) sx += xs[rr * 32 + t];
        xinv[t] = 1.0f / fmaxf(sqrtf(sx), 1e-8f);
    }
    __syncthreads();

    // ---- scaled f32 store. class = w*64+tm*16+quad*4+i ; pixel = p0+tn*16+m16 ----
    float inv2[2];
#pragma unroll
    for (int tn = 0; tn < 2; ++tn) inv2[tn] = xinv[tn * 16 + m16];
#pragma unroll
    for (int tm = 0; tm < 4; ++tm) {
        const int cbase = w * 64 + tm * 16 + quad * 4;
        const f32x4 rs4 = *(const f32x4*)(rs_ws + cbase);
#pragma unroll
        for (int tn = 0; tn < 2; ++tn) {
#pragma unroll
            for (int i = 0; i < 4; ++i) {
                Og[(size_t)(cbase + i) * P + p0 + tn * 16 + m16] =
                    acc[tm][tn][i] * rs4[i] * inv2[tn];
            }
        }
    }
}

extern "C" void kernel_launch(void* const* d_in, const int* in_sizes, int n_in,
                              void* d_out, int out_size, void* d_ws, size_t ws_size,
                              hipStream_t stream) {
    (void)out_size; (void)ws_size;
    const void* X = d_in[0];
    const void* W = d_in[1];
    const void* S = d_in[2];
    for (int i = 0; i < n_in; ++i) {
        if (in_sizes[i] == 256 * 65536) X = d_in[i];
        else if (in_sizes[i] == 256 * 256) W = d_in[i];
        else if (in_sizes[i] == 256)      S = d_in[i];
    }
    float* rs  = (float*)d_ws;
    u16*   wbf = (u16*)((char*)d_ws + 1024);   // 128 KB bf16 W image
    coshead_prep<<<dim3(256), dim3(64), 0, stream>>>(X, W, S, rs, wbf);
    coshead_gemm<<<dim3(2048), dim3(256), 0, stream>>>(X, wbf, rs, (float*)d_out);
}

// Round 13
// 131.560 us; speedup vs baseline: 1.1953x; 1.0189x over previous
//
#include <hip/hip_runtime.h>
#include <stdint.h>

typedef unsigned short u16;
typedef __bf16 bf16_t;
typedef bf16_t bf16x8 __attribute__((ext_vector_type(8)));
typedef float f32x4 __attribute__((ext_vector_type(4)));

static constexpr int P = 65536;  // H*W; D = C = 256

__device__ __forceinline__ float bfbits2f(uint32_t b) {
    union { uint32_t i; float f; } u; u.i = b << 16; return u.f;
}
__device__ __forceinline__ u16 f2bf(float f) {
    union { float f; uint32_t i; } u; u.f = f;
    uint32_t x = u.i + 0x7FFFu + ((u.i >> 16) & 1u);   // RNE
    return (u16)(x >> 16);
}
__device__ __forceinline__ uint32_t pack2(float a, float b) {
    return (uint32_t)f2bf(a) | ((uint32_t)f2bf(b) << 16);
}

// Runtime input-dtype sniff (insurance; verdict on this harness: f32).
__device__ __forceinline__ int detect_bf16_input(const void* Xg) {
    const uint32_t* Xu = (const uint32_t*)Xg;
    const int lane = (int)(threadIdx.x & 63);
    const uint32_t v = Xu[(size_t)lane * 131071u];
    const uint32_t e = (v >> 7) & 0xFFu;
    unsigned long long m = __ballot(e >= 96u && e <= 135u);
    return __popcll(m) >= 40;
}

// Kernel 1: rs[c] = scale[c]*5/max(||w_c||,1e-8)  AND  W -> bf16 row image.
__global__ __launch_bounds__(64) void coshead_prep(
    const void* __restrict__ Xg, const void* __restrict__ Wg,
    const void* __restrict__ Sg, float* __restrict__ rs_ws,
    u16* __restrict__ wbf)
{
    const int c    = (int)blockIdx.x;
    const int lane = (int)threadIdx.x;
    const int bf   = detect_bf16_input(Xg);
    float s;
    uint2 packed;
    if (bf) {
        const uint2 v = *(const uint2*)((const u16*)Wg + (size_t)c * 256 + lane * 4);
        const float a = bfbits2f(v.x & 0xFFFFu), b = bfbits2f(v.x >> 16);
        const float d = bfbits2f(v.y & 0xFFFFu), e = bfbits2f(v.y >> 16);
        s = a * a + b * b + d * d + e * e;
        packed = v;
    } else {
        const f32x4 v = *(const f32x4*)((const float*)Wg + (size_t)c * 256 + lane * 4);
        s = v[0] * v[0] + v[1] * v[1] + v[2] * v[2] + v[3] * v[3];
        packed.x = pack2(v[0], v[1]);
        packed.y = pack2(v[2], v[3]);
    }
    *(uint2*)(wbf + (size_t)c * 256 + lane * 4) = packed;
    s += __shfl_xor(s, 1);  s += __shfl_xor(s, 2);  s += __shfl_xor(s, 4);
    s += __shfl_xor(s, 8);  s += __shfl_xor(s, 16); s += __shfl_xor(s, 32);
    if (lane == 0) {
        const float sc = bf ? bfbits2f((uint32_t)((const u16*)Sg)[c])
                            : ((const float*)Sg)[c];
        rs_ws[c] = sc * 5.0f / fmaxf(sqrtf(s), 1e-8f);
    }
}

// Kernel 2: out[c,p] = (W@X)[c,p] * rs[c] / max(||x_p||,1e-8), f32 out.
// WHOLE-W-IN-LDS, vm-drain-free steady state:
//   - grid 256, 1 block/CU (LDS 144 KB); __launch_bounds__(256,1) -> 512-reg
//     budget => the 16-reg X carry CANNOT spill (kills the R1/R2/R3/R9 mode).
//   - prologue stages all of W (128 KB) into LDS via 32 global_load_lds/wave.
//   - 16 iterations (4 ptiles x 4 kc): pack X[i] (regs->sB dbuf, fused ssq)
//     -> issue X[i+1] loads -> lgkmcnt(0) + RAW s_barrier (NEVER vmcnt(0))
//     -> MFMA (ds_read only). The X[i+1] load drains naturally at its
//     consumption in iteration i+1, hidden under barrier+MFMA+epilogue.
//   - in-order vmcnt is safe by ISSUE ORDER: W-DMA < X[0]; X[i] < stores[pt]
//     < X[i+1]-consume waits use counted vmcnt leaving stores in flight.
// Swizzles / pack / ssq / reduce / MFMA orders identical to R8 => absmax same.
__global__ __launch_bounds__(256, 1) void coshead_gemm(
    const void* __restrict__ Xg_, const u16* __restrict__ Wbf,
    const float* __restrict__ rs_ws, float* __restrict__ Og)
{
    __shared__ char smem_[131072 + 16384 + 256];
    char*  sA   = smem_;                      // [4 kc][256 rows][8 slots x 16 B]
    char*  sB   = smem_ + 131072;             // [2][64 pix][8 slots x 16 B] dbuf
    float* xinv = (float*)(smem_ + 131072 + 16384);  // [64]

    const int t  = (int)threadIdx.x;
    const int l  = t & 63;
    const int w  = t >> 6;
    const int pbase = (int)blockIdx.x * 256;
    const int bf = detect_bf16_input(Xg_);

    const int g    = t & 7;      // pixel octet
    const int r    = t >> 3;     // k-pair row 0..31
    const int m16  = l & 15;
    const int quad = l >> 4;

    // ---- prologue: stage ALL of W. Chunk kc at sA+kc*32768 uses the R8
    // layout; call (j,kc) covers rows j*32 + w*8 .. +7 of chunk kc. ----
    const int lrow = l >> 3;
    const int gsl  = (l & 7) ^ lrow;
    const u16* wsrc = Wbf + ((size_t)(w * 8 + lrow) << 8) + gsl * 8;
    char* ldsA = sA + w * 1024;
#pragma unroll
    for (int j = 0; j < 8; ++j)
#pragma unroll
        for (int kc = 0; kc < 4; ++kc)
            __builtin_amdgcn_global_load_lds(
                (const __attribute__((address_space(1))) void*)(wsrc + j * 8192 + kc * 64),
                (__attribute__((address_space(3))) void*)(ldsA + kc * 32768 + j * 4096),
                16, 0, 0);

    // ---- X prefetch for iteration 0 (issued AFTER W-DMA: consuming these
    // regs auto-drains the older W-DMA before the first barrier) ----
    f32x4 rA, rB, rC, rD;          // f32 carry
    uint4 vb0, vb1;                // bf16 carry
    if (bf) {
        const u16* xp = (const u16*)Xg_ + (size_t)(2 * r) * P + pbase + g * 8;
        vb0 = *(const uint4*)xp;
        vb1 = *(const uint4*)(xp + P);
    } else {
        const float* xp = (const float*)Xg_ + (size_t)(2 * r) * P + pbase + g * 8;
        rA = *(const f32x4*)xp;
        rB = *(const f32x4*)(xp + 4);
        rC = *(const f32x4*)(xp + P);
        rD = *(const f32x4*)(xp + P + 4);
    }

    for (int pt = 0; pt < 4; ++pt) {
        const int p0 = pbase + pt * 64;

        float ssq[8];
#pragma unroll
        for (int j = 0; j < 8; ++j) ssq[j] = 0.f;
        f32x4 acc[4][4];
#pragma unroll
        for (int a = 0; a < 4; ++a)
#pragma unroll
            for (int b = 0; b < 4; ++b)
#pragma unroll
                for (int i = 0; i < 4; ++i) acc[a][b][i] = 0.f;

        for (int kc = 0; kc < 4; ++kc) {
            char* sBw = sB + (kc & 1) * 8192;

            // ---- pack carried X regs -> sBw (fused ssq), R8 formulas ----
            if (bf) {
                const uint32_t e0[4] = {vb0.x, vb0.y, vb0.z, vb0.w};
                const uint32_t e1[4] = {vb1.x, vb1.y, vb1.z, vb1.w};
#pragma unroll
                for (int d = 0; d < 4; ++d) {
                    const float f00 = bfbits2f(e0[d] & 0xFFFFu), f01 = bfbits2f(e0[d] >> 16);
                    const float f10 = bfbits2f(e1[d] & 0xFFFFu), f11 = bfbits2f(e1[d] >> 16);
                    ssq[2 * d]     += f00 * f00 + f10 * f10;
                    ssq[2 * d + 1] += f01 * f01 + f11 * f11;
                    const uint32_t d0 = (e0[d] & 0xFFFFu) | (e1[d] << 16);
                    const uint32_t d1 = (e0[d] >> 16) | (e1[d] & 0xFFFF0000u);
                    const int pj0 = g * 8 + 2 * d, pj1 = pj0 + 1;
                    *(uint32_t*)(sBw + pj0 * 128 + (((r >> 2) ^ (pj0 & 7) ^ g) * 16) + (r & 3) * 4) = d0;
                    *(uint32_t*)(sBw + pj1 * 128 + (((r >> 2) ^ (pj1 & 7) ^ g) * 16) + (r & 3) * 4) = d1;
                }
            } else {
                const float f0[8] = {rA[0], rA[1], rA[2], rA[3], rB[0], rB[1], rB[2], rB[3]};
                const float f1[8] = {rC[0], rC[1], rC[2], rC[3], rD[0], rD[1], rD[2], rD[3]};
#pragma unroll
                for (int j = 0; j < 8; ++j) {
                    ssq[j] += f0[j] * f0[j] + f1[j] * f1[j];
                    const int pix = g * 8 + j;
                    *(uint32_t*)(sBw + pix * 128 + (((r >> 2) ^ (pix & 7) ^ g) * 16) + (r & 3) * 4) =
                        pack2(f0[j], f1[j]);
                }
            }

            // ---- issue next iteration's X loads (survive barrier+MFMA[+epi]) ----
            const int it = pt * 4 + kc;
            if (it < 15) {
                const int nk = (it + 1) & 3, np = (it + 1) >> 2;
                if (bf) {
                    const u16* xp = (const u16*)Xg_ + (size_t)(2 * r + nk * 64) * P
                                    + pbase + np * 64 + g * 8;
                    vb0 = *(const uint4*)xp;
                    vb1 = *(const uint4*)(xp + P);
                } else {
                    const float* xp = (const float*)Xg_ + (size_t)(2 * r + nk * 64) * P
                                      + pbase + np * 64 + g * 8;
                    rA = *(const f32x4*)xp;
                    rB = *(const f32x4*)(xp + 4);
                    rC = *(const f32x4*)(xp + P);
                    rD = *(const f32x4*)(xp + P + 4);
                }
            }

            // ---- raw barrier: LDS visibility only, NO vm drain ----
            asm volatile("s_waitcnt lgkmcnt(0)" ::: "memory");
            __builtin_amdgcn_sched_barrier(0);
            __builtin_amdgcn_s_barrier();

            // ---- MFMA: ds_read only (A from resident sA chunk kc) ----
            const char* sAk = sA + kc * 32768;
#pragma unroll
            for (int kk = 0; kk < 2; ++kk) {
                bf16x8 af[4], bfr[4];
#pragma unroll
                for (int tm = 0; tm < 4; ++tm) {
                    const int row = w * 64 + tm * 16 + m16;
                    af[tm] = *(const bf16x8*)(sAk + row * 128 + (((kk * 4 + quad) ^ (row & 7)) * 16));
                }
#pragma unroll
                for (int tn = 0; tn < 4; ++tn) {
                    const int pix = tn * 16 + m16;
                    bfr[tn] = *(const bf16x8*)(sBw + pix * 128 +
                               (((kk * 4 + quad) ^ (pix & 7) ^ (pix >> 3)) * 16));
                }
#pragma unroll
                for (int tm = 0; tm < 4; ++tm)
#pragma unroll
                    for (int tn = 0; tn < 4; ++tn)
                        acc[tm][tn] = __builtin_amdgcn_mfma_f32_16x16x32_bf16(
                            af[tm], bfr[tn], acc[tm][tn], 0, 0, 0);
            }
            // no trailing barrier: next pack writes the OTHER sB buffer, and
            // any same-buffer rewrite is 2 barriers away (program order).
        }

        // ---- ptile epilogue (raw barriers; X[pt+1,0] stays in flight) ----
        // xs lives in sB buffer1 (dead: all MFMA[pt,3] reads done at barrier).
        float* xs = (float*)(sB + 8192);
        asm volatile("s_waitcnt lgkmcnt(0)" ::: "memory");
        __builtin_amdgcn_sched_barrier(0);
        __builtin_amdgcn_s_barrier();          // all waves done MFMA[pt,3]
#pragma unroll
        for (int j = 0; j < 8; ++j) xs[r * 64 + g * 8 + j] = ssq[j];
        asm volatile("s_waitcnt lgkmcnt(0)" ::: "memory");
        __builtin_amdgcn_sched_barrier(0);
        __builtin_amdgcn_s_barrier();          // xs visible
        if (t < 64) {
            float sx = 0.f;
#pragma unroll
            for (int rr = 0; rr < 32; ++rr) sx += xs[rr * 64 + t];
            xinv[t] = 1.0f / fmaxf(sqrtf(sx), 1e-8f);
        }
        asm volatile("s_waitcnt lgkmcnt(0)" ::: "memory");
        __builtin_amdgcn_sched_barrier(0);
        __builtin_amdgcn_s_barrier();          // xinv visible

        // ---- scaled f32 store (class = w*64+tm*16+quad*4+i ; pixel = p0+tn*16+m16) ----
        float inv4[4];
#pragma unroll
        for (int tn = 0; tn < 4; ++tn) inv4[tn] = xinv[tn * 16 + m16];
#pragma unroll
        for (int tm = 0; tm < 4; ++tm) {
            const int cbase = w * 64 + tm * 16 + quad * 4;
            const f32x4 rs4 = *(const f32x4*)(rs_ws + cbase);
#pragma unroll
            for (int tn = 0; tn < 4; ++tn) {
#pragma unroll
                for (int i = 0; i < 4; ++i) {
                    Og[(size_t)(cbase + i) * P + p0 + tn * 16 + m16] =
                        acc[tm][tn][i] * rs4[i] * inv4[tn];
                }
            }
        }
        // no barrier here: next ptile's first pack writes sB buffer0, which
        // nobody reads until after the next kc-loop barrier; xinv next write
        // is 3 barriers away.
    }
}

extern "C" void kernel_launch(void* const* d_in, const int* in_sizes, int n_in,
                              void* d_out, int out_size, void* d_ws, size_t ws_size,
                              hipStream_t stream) {
    (void)out_size; (void)ws_size;
    const void* X = d_in[0];
    const void* W = d_in[1];
    const void* S = d_in[2];
    for (int i = 0; i < n_in; ++i) {
        if (in_sizes[i] == 256 * 65536) X = d_in[i];
        else if (in_sizes[i] == 256 * 256) W = d_in[i];
        else if (in_sizes[i] == 256)      S = d_in[i];
    }
    float* rs  = (float*)d_ws;
    u16*   wbf = (u16*)((char*)d_ws + 1024);   // 128 KB bf16 W image
    coshead_prep<<<dim3(256), dim3(64), 0, stream>>>(X, W, S, rs, wbf);
    coshead_gemm<<<dim3(256), dim3(256), 0, stream>>>(X, wbf, rs, (float*)d_out);
}